// Round 7
// baseline (357.432 us; speedup 1.0000x reference)
//
#include <hip/hip_runtime.h>
#include <math.h>

// VQQuantizer eval, round 7.
// Scorer unchanged from round 6 (hi-only bf16 MFMA, margin 0.017*||h||,
// provably >= 2x the bf16 truncation error; 256x256 tile BK=32 dbuf).
// k_finalize (230us, latency-bound) split into:
//   k_select: one WAVE per row, ballot-driven fp64 candidate rescoring
//             (+ cnt-triggered stripe rescan) -> exact argmax vs f64 ref.
//   k_write:  pure-bandwidth streaming of q/ct/ch/cq + fp64 loss partials,
//             reading the normalized codebook (cbn, 2MB, L2-resident).

#define NROWS 32768
#define DDIM  512
#define KCODE 1024
#define MARGIN_COEF 0.017f

typedef __attribute__((address_space(1))) const void gvoid_t;
typedef __attribute__((address_space(3))) void svoid_t;
typedef float f32x4 __attribute__((ext_vector_type(4)));
typedef short bf16x8 __attribute__((ext_vector_type(8)));

__device__ __forceinline__ void gl16(const void* g, void* s) {
  __builtin_amdgcn_global_load_lds((gvoid_t*)g, (svoid_t*)s, 16, 0, 0);
}
// round-to-nearest-even f32 -> bf16 (finite inputs only)
__device__ __forceinline__ unsigned short f2bf(float x) {
  unsigned u = __float_as_uint(x);
  u = u + 0x7fffu + ((u >> 16) & 1u);
  return (unsigned short)(u >> 16);
}

// ------ codebook inverse norms + normalized codebook (f32 of fp64 math) -----
__global__ __launch_bounds__(256) void k_invc(const float* __restrict__ x,
                                              double* __restrict__ invd,
                                              float* __restrict__ invf,
                                              float* __restrict__ cbn) {
  const int lane = threadIdx.x & 63;
  const int row = blockIdx.x * 4 + (threadIdx.x >> 6);
  const float* p = x + (size_t)row * DDIM;
  float4 v0 = *(const float4*)(p + lane * 4);
  float4 v1 = *(const float4*)(p + 256 + lane * 4);
  double s = (double)v0.x * v0.x + (double)v0.y * v0.y + (double)v0.z * v0.z + (double)v0.w * v0.w
           + (double)v1.x * v1.x + (double)v1.y * v1.y + (double)v1.z * v1.z + (double)v1.w * v1.w;
  #pragma unroll
  for (int m = 1; m < 64; m <<= 1) s += __shfl_xor(s, m);
  const double iv = 1.0 / fmax(sqrt(s), 1e-6);
  float4 n0, n1;
  n0.x = (float)((double)v0.x * iv); n0.y = (float)((double)v0.y * iv);
  n0.z = (float)((double)v0.z * iv); n0.w = (float)((double)v0.w * iv);
  n1.x = (float)((double)v1.x * iv); n1.y = (float)((double)v1.y * iv);
  n1.z = (float)((double)v1.z * iv); n1.w = (float)((double)v1.w * iv);
  *(float4*)(cbn + (size_t)row * DDIM + lane * 4) = n0;
  *(float4*)(cbn + (size_t)row * DDIM + 256 + lane * 4) = n1;
  if (lane == 0) {
    invd[row] = iv;
    invf[row] = (float)iv;
  }
}

// ------- prep: bf16-hi fragment-tiled + per-row norm (fused) ----------
__global__ __launch_bounds__(256) void k_prep(const float* __restrict__ src,
                                              unsigned short* __restrict__ hi,
                                              float* __restrict__ nrm) {
  const int tile = blockIdx.x;
  const int t = threadIdx.x;
  const int r = t >> 4;
  const int l16 = t & 15;
  const float4* s4 = (const float4*)(src + (size_t)tile * 16 * DDIM);
  double ss = 0.0;
  #pragma unroll
  for (int j = 0; j < 8; ++j) {
    const int f4 = r * 128 + l16 + j * 16;
    float4 v = s4[f4];
    ss += (double)v.x * v.x + (double)v.y * v.y + (double)v.z * v.z + (double)v.w * v.w;
    const int k = (l16 + j * 16) * 4;
    const int kc = k >> 5;
    const int l = r | (((k >> 3) & 3) << 4);
    ushort4 h4;
    h4.x = f2bf(v.x); h4.y = f2bf(v.y); h4.z = f2bf(v.z); h4.w = f2bf(v.w);
    *(ushort4*)(hi + (size_t)tile * 8192 + kc * 512 + l * 8 + (k & 7)) = h4;
  }
  #pragma unroll
  for (int m = 1; m < 16; m <<= 1) ss += __shfl_xor(ss, m);
  if (l16 == 0) nrm[tile * 16 + r] = (float)sqrt(ss);
}

// ---------------- MFMA scorer: 256x256 tile, hi-only, BK=32 ----------------
__global__ __launch_bounds__(512) void k_mfma(const unsigned short* __restrict__ AThi,
                                              const unsigned short* __restrict__ BThi,
                                              const float* __restrict__ invcf,
                                              const float* __restrict__ hnormf,
                                              float4* __restrict__ pcand,
                                              int* __restrict__ pcnt) {
  __shared__ bf16x8 lds[4096];
  const int tx = threadIdx.x;
  const int bid = blockIdx.x;
  const int pr = (bid & 7) * 16 + (bid >> 5);
  const int pc = (bid >> 3) & 3;
  const int lane = tx & 63;
  const int wid = tx >> 6;
  const int wr = wid >> 1;
  const int wc = wid & 1;

  f32x4 acc[4][8];
  #pragma unroll
  for (int m = 0; m < 4; ++m)
    #pragma unroll
    for (int n = 0; n < 8; ++n) acc[m][n] = (f32x4)(0.0f);

  const int s0 = tx, s1 = tx + 512;
  const size_t a0 = (size_t)(pr * 16 + (s0 >> 6)) * 8192 + (s0 & 63) * 8;
  const size_t a1 = (size_t)(pr * 16 + (s1 >> 6)) * 8192 + (s1 & 63) * 8;
  const size_t b0 = (size_t)(pc * 16 + (s0 >> 6)) * 8192 + (s0 & 63) * 8;
  const size_t b1 = (size_t)(pc * 16 + (s1 >> 6)) * 8192 + (s1 & 63) * 8;

  gl16(AThi + a0, &lds[s0]);
  gl16(AThi + a1, &lds[s1]);
  gl16(BThi + b0, &lds[1024 + s0]);
  gl16(BThi + b1, &lds[1024 + s1]);
  __syncthreads();

  int cur = 0;
  for (int kc = 0; kc < 16; ++kc) {
    if (kc < 15) {
      const int off = (kc + 1) * 512;
      bf16x8* base = &lds[(cur ^ 1) * 2048];
      gl16(AThi + a0 + off, base + s0);
      gl16(AThi + a1 + off, base + s1);
      gl16(BThi + b0 + off, base + 1024 + s0);
      gl16(BThi + b1 + off, base + 1024 + s1);
    }
    const bf16x8* L = &lds[cur * 2048];
    bf16x8 af[4], bq[8];
    #pragma unroll
    for (int m = 0; m < 4; ++m) af[m] = L[(wr * 4 + m) * 64 + lane];
    #pragma unroll
    for (int n = 0; n < 8; ++n) bq[n] = L[1024 + (wc * 8 + n) * 64 + lane];
    #pragma unroll
    for (int m = 0; m < 4; ++m)
      #pragma unroll
      for (int n = 0; n < 8; ++n)
        acc[m][n] = __builtin_amdgcn_mfma_f32_16x16x32_bf16(af[m], bq[n], acc[m][n], 0, 0, 0);
    __syncthreads();
    cur ^= 1;
  }

  const int q = lane >> 4;
  const int c16 = lane & 15;
  const int rowbase = pr * 256 + wr * 64;

  #pragma unroll
  for (int hn = 0; hn < 2; ++hn) {
    const int colbase = pc * 256 + wc * 128 + hn * 64;
    const int st = colbase >> 6;
    float invn[4];
    #pragma unroll
    for (int n4 = 0; n4 < 4; ++n4) invn[n4] = invcf[colbase + n4 * 16 + c16];

    #pragma unroll
    for (int m = 0; m < 4; ++m) {
      #pragma unroll
      for (int r = 0; r < 4; ++r) {
        const int row = rowbase + m * 16 + q * 4 + r;
        float sv[4];
        #pragma unroll
        for (int n4 = 0; n4 < 4; ++n4) sv[n4] = acc[m][hn * 4 + n4][r] * invn[n4];

        float t1 = sv[0]; int i1 = colbase + c16;
        #pragma unroll
        for (int n4 = 1; n4 < 4; ++n4) {
          const int idx = colbase + n4 * 16 + c16;
          if (sv[n4] > t1) { t1 = sv[n4]; i1 = idx; }
        }
        #pragma unroll
        for (int msk = 1; msk < 16; msk <<= 1) {
          float os = __shfl_xor(t1, msk); int oi = __shfl_xor(i1, msk);
          if (os > t1 || (os == t1 && oi < i1)) { t1 = os; i1 = oi; }
        }

        const float thr = t1 - MARGIN_COEF * hnormf[row];
        int cnt = 0;
        float t2 = -3.4e38f; int i2 = 0x7fffffff;
        #pragma unroll
        for (int n4 = 0; n4 < 4; ++n4) {
          const int idx = colbase + n4 * 16 + c16;
          cnt += (sv[n4] >= thr);
          if (idx != i1 && sv[n4] > t2) { t2 = sv[n4]; i2 = idx; }
        }
        #pragma unroll
        for (int msk = 1; msk < 16; msk <<= 1) {
          cnt += __shfl_xor(cnt, msk);
          float os = __shfl_xor(t2, msk); int oi = __shfl_xor(i2, msk);
          if (os > t2 || (os == t2 && oi < i2)) { t2 = os; i2 = oi; }
        }

        if (c16 == 0) {
          pcand[(size_t)row * 16 + st] = make_float4(t1, __int_as_float(i1), t2, __int_as_float(i2));
          pcnt[(size_t)row * 16 + st] = cnt;
        }
      }
    }
  }
}

// ---------------- select: one wave per row, fp64 exact argmax ----------------
__global__ __launch_bounds__(256) void k_select(const float* __restrict__ h,
                                                const float* __restrict__ cb,
                                                const double* __restrict__ invcd,
                                                const float* __restrict__ hnormf,
                                                const float4* __restrict__ pcand,
                                                const int* __restrict__ pcnt,
                                                int* __restrict__ sidxb,
                                                float* __restrict__ out_idx) {
  const int lane = threadIdx.x & 63;
  const int row = blockIdx.x * 4 + (threadIdx.x >> 6);

  float4 pc4 = make_float4(-3.4e38f, 0.0f, -3.4e38f, 0.0f);
  int ct = 0;
  if (lane < 16) {
    pc4 = pcand[(size_t)row * 16 + lane];
    ct = pcnt[(size_t)row * 16 + lane];
  }
  float best = pc4.x;
  #pragma unroll
  for (int m = 1; m < 64; m <<= 1) best = fmaxf(best, __shfl_xor(best, m));
  const float thr = best - MARGIN_COEF * hnormf[row];

  const unsigned long long m1 = __ballot(pc4.x >= thr);
  const unsigned long long m2 = __ballot(pc4.z >= thr);
  const unsigned long long mr = __ballot((pc4.z >= thr) && (ct > 2));

  // h row in registers (8 floats/lane)
  const float4* hp = (const float4*)(h + (size_t)row * DDIM + lane * 8);
  const float4 h0 = hp[0], h1 = hp[1];

  double bs = -1e300; int bi = 0x7fffffff;
  const int i1 = __float_as_int(pc4.y);
  const int i2 = __float_as_int(pc4.w);

  // candidate rescoring (fp64)
  #define RESCORE(codeexpr)                                                  \
    {                                                                        \
      const int code = (codeexpr);                                           \
      const float4* cp = (const float4*)(cb + (size_t)code * DDIM + lane*8); \
      const float4 c0 = cp[0], c1 = cp[1];                                   \
      double p = (double)h0.x * c0.x + (double)h0.y * c0.y                   \
               + (double)h0.z * c0.z + (double)h0.w * c0.w                   \
               + (double)h1.x * c1.x + (double)h1.y * c1.y                   \
               + (double)h1.z * c1.z + (double)h1.w * c1.w;                  \
      _Pragma("unroll")                                                      \
      for (int m = 1; m < 64; m <<= 1) p += __shfl_xor(p, m);                \
      const double sc = p * invcd[code];                                     \
      if (sc > bs || (sc == bs && code < bi)) { bs = sc; bi = code; }        \
    }

  for (unsigned long long mm = m1; mm; mm &= mm - 1)
    RESCORE(__shfl(i1, __builtin_ctzll(mm)));
  for (unsigned long long mm = m2; mm; mm &= mm - 1)
    RESCORE(__shfl(i2, __builtin_ctzll(mm)));
  for (unsigned long long mm = mr; mm; mm &= mm - 1) {
    const int st = __builtin_ctzll(mm);
    for (int j = 0; j < 64; ++j) RESCORE(st * 64 + j);
  }
  #undef RESCORE

  if (lane == 0) {
    sidxb[row] = bi;
    out_idx[row] = (float)bi;
  }
}

// ---------------- write: pure-bandwidth outputs + loss partials -------------
// 256 thr = 8 rows/block (32 lanes per row). Per row: q one-hot (4KB, zeros
// synthesized in regs), ct/ch/cq = cbn[bi] (2KB each), fp64 loss partial.
__global__ __launch_bounds__(256) void k_write(const float* __restrict__ h,
                                               const float* __restrict__ cbn,
                                               const int* __restrict__ sidxb,
                                               float* __restrict__ out_q,
                                               float* __restrict__ out_ct,
                                               float* __restrict__ out_ch,
                                               float* __restrict__ out_cq,
                                               double* __restrict__ lsum) {
  const int tx = threadIdx.x;
  const int r = blockIdx.x * 8 + (tx >> 5);
  const int g = tx & 31;
  const int bi = sidxb[r];

  // q one-hot: 8 x float4, col = g*4 + j*128 (each j: 512B contiguous/32 lanes)
  {
    float* qrow = out_q + (size_t)r * KCODE;
    #pragma unroll
    for (int j = 0; j < 8; ++j) {
      const int col = g * 4 + j * 128;
      float4 qv;
      qv.x = (col + 0 == bi) ? 1.0f : 0.0f;
      qv.y = (col + 1 == bi) ? 1.0f : 0.0f;
      qv.z = (col + 2 == bi) ? 1.0f : 0.0f;
      qv.w = (col + 3 == bi) ? 1.0f : 0.0f;
      *(float4*)(qrow + col) = qv;
    }
  }

  // h row (16 floats) + cbn row; norm, then loss partial + 3 output writes
  float4 hvv[4], cvv[4];
  const float* hrow = h + (size_t)r * DDIM;
  const float* crow = cbn + (size_t)bi * DDIM;
  #pragma unroll
  for (int j = 0; j < 4; ++j) {
    const int col = g * 4 + j * 128;
    hvv[j] = *(const float4*)(hrow + col);
    cvv[j] = *(const float4*)(crow + col);
  }
  double hs = 0.0;
  #pragma unroll
  for (int j = 0; j < 4; ++j)
    hs += (double)hvv[j].x * hvv[j].x + (double)hvv[j].y * hvv[j].y
        + (double)hvv[j].z * hvv[j].z + (double)hvv[j].w * hvv[j].w;
  #pragma unroll
  for (int m = 1; m < 32; m <<= 1) hs += __shfl_xor(hs, m);
  const double ih = 1.0 / fmax(sqrt(hs), 1e-6);

  double ls = 0.0;
  #pragma unroll
  for (int j = 0; j < 4; ++j) {
    const int col = g * 4 + j * 128;
    const size_t ro = (size_t)r * DDIM + col;
    *(float4*)(out_ct + ro) = cvv[j];
    *(float4*)(out_ch + ro) = cvv[j];
    *(float4*)(out_cq + ro) = cvv[j];
    double e;
    e = (double)hvv[j].x * ih - (double)cvv[j].x; ls += e * e;
    e = (double)hvv[j].y * ih - (double)cvv[j].y; ls += e * e;
    e = (double)hvv[j].z * ih - (double)cvv[j].z; ls += e * e;
    e = (double)hvv[j].w * ih - (double)cvv[j].w; ls += e * e;
  }
  #pragma unroll
  for (int m = 1; m < 32; m <<= 1) ls += __shfl_xor(ls, m);
  if (g == 0) lsum[r] = ls;
}

__global__ __launch_bounds__(256) void k_loss(const double* __restrict__ lsum,
                                              float* __restrict__ out_loss) {
  const int tx = threadIdx.x;
  double s = 0.0;
  for (int i = tx; i < NROWS; i += 256) s += lsum[i];
  #pragma unroll
  for (int m = 1; m < 64; m <<= 1) s += __shfl_xor(s, m);
  __shared__ double sh[4];
  if ((tx & 63) == 0) sh[tx >> 6] = s;
  __syncthreads();
  if (tx == 0)
    out_loss[0] = (float)(1.25 * (sh[0] + sh[1] + sh[2] + sh[3]) / ((double)NROWS * (double)DDIM));
}

extern "C" void kernel_launch(void* const* d_in, const int* in_sizes, int n_in,
                              void* d_out, int out_size, void* d_ws, size_t ws_size,
                              hipStream_t stream) {
  const float* h = (const float*)d_in[0];
  const float* cb = (const float*)d_in[1];

  float* out = (float*)d_out;
  float* out_q    = out;
  float* out_ct   = out + 33554432;
  float* out_ch   = out + 50331648;
  float* out_cq   = out + 67108864;
  float* out_loss = out + 83886080;
  float* out_idx  = out + 83886081;

  char* ws = (char*)d_ws;
  unsigned short* AThi = (unsigned short*)(ws);               // 32 MB
  unsigned short* BThi = (unsigned short*)(ws + 33554432);    // 1 MB
  double* invcd  = (double*)(ws + 34603008);                  // 8 KB
  float*  invcf  = (float*)(ws + 34611200);                   // 4 KB
  float*  hnormf = (float*)(ws + 34615296);                   // 128 KB
  float*  cbnrm  = (float*)(ws + 34746368);                   // 4 KB (sink)
  float*  cbn    = (float*)(ws + 34750464);                   // 2 MB
  float4* pcand  = (float4*)(ws + 36847616);                  // 8 MB
  int*    pcnt   = (int*)(ws + 45236224);                     // 2 MB
  double* lsum   = (double*)(ws + 47333376);                  // 256 KB
  int*    sidxb  = (int*)(ws + 47595520);                     // 128 KB

  k_invc<<<KCODE / 4, 256, 0, stream>>>(cb, invcd, invcf, cbn);
  k_prep<<<NROWS / 16, 256, 0, stream>>>(h, AThi, hnormf);
  k_prep<<<KCODE / 16, 256, 0, stream>>>(cb, BThi, cbnrm);
  k_mfma<<<512, 512, 0, stream>>>(AThi, BThi, invcf, hnormf, pcand, pcnt);
  k_select<<<NROWS / 4, 256, 0, stream>>>(h, cb, invcd, hnormf, pcand, pcnt,
                                          sidxb, out_idx);
  k_write<<<NROWS / 8, 256, 0, stream>>>(h, cbn, sidxb,
                                         out_q, out_ct, out_ch, out_cq, lsum);
  k_loss<<<1, 256, 0, stream>>>(lsum, out_loss);
}

// Round 8
// 317.237 us; speedup vs baseline: 1.1267x; 1.1267x over previous
//
#include <hip/hip_runtime.h>
#include <math.h>

// VQQuantizer eval, round 8.
// = round 7 with the stripe-rescan trigger fixed: the mfma epilogue now stores
// the stripe's 3rd-best score t3 (instead of a stripe-local in-margin count),
// and k_select rescans a stripe iff t3 >= global_threshold. Any potential
// argmax not in its stripe's top-2 has obs <= t3 and obs >= thr, so the
// trigger provably covers it -- and it almost never fires (vs ~20% before,
// which was the hidden 150-230us cost in rounds 6/7).

#define NROWS 32768
#define DDIM  512
#define KCODE 1024
#define MARGIN_COEF 0.017f

typedef __attribute__((address_space(1))) const void gvoid_t;
typedef __attribute__((address_space(3))) void svoid_t;
typedef float f32x4 __attribute__((ext_vector_type(4)));
typedef short bf16x8 __attribute__((ext_vector_type(8)));

__device__ __forceinline__ void gl16(const void* g, void* s) {
  __builtin_amdgcn_global_load_lds((gvoid_t*)g, (svoid_t*)s, 16, 0, 0);
}
// round-to-nearest-even f32 -> bf16 (finite inputs only)
__device__ __forceinline__ unsigned short f2bf(float x) {
  unsigned u = __float_as_uint(x);
  u = u + 0x7fffu + ((u >> 16) & 1u);
  return (unsigned short)(u >> 16);
}

// ------ codebook inverse norms + normalized codebook (f32 of fp64 math) -----
__global__ __launch_bounds__(256) void k_invc(const float* __restrict__ x,
                                              double* __restrict__ invd,
                                              float* __restrict__ invf,
                                              float* __restrict__ cbn) {
  const int lane = threadIdx.x & 63;
  const int row = blockIdx.x * 4 + (threadIdx.x >> 6);
  const float* p = x + (size_t)row * DDIM;
  float4 v0 = *(const float4*)(p + lane * 4);
  float4 v1 = *(const float4*)(p + 256 + lane * 4);
  double s = (double)v0.x * v0.x + (double)v0.y * v0.y + (double)v0.z * v0.z + (double)v0.w * v0.w
           + (double)v1.x * v1.x + (double)v1.y * v1.y + (double)v1.z * v1.z + (double)v1.w * v1.w;
  #pragma unroll
  for (int m = 1; m < 64; m <<= 1) s += __shfl_xor(s, m);
  const double iv = 1.0 / fmax(sqrt(s), 1e-6);
  float4 n0, n1;
  n0.x = (float)((double)v0.x * iv); n0.y = (float)((double)v0.y * iv);
  n0.z = (float)((double)v0.z * iv); n0.w = (float)((double)v0.w * iv);
  n1.x = (float)((double)v1.x * iv); n1.y = (float)((double)v1.y * iv);
  n1.z = (float)((double)v1.z * iv); n1.w = (float)((double)v1.w * iv);
  *(float4*)(cbn + (size_t)row * DDIM + lane * 4) = n0;
  *(float4*)(cbn + (size_t)row * DDIM + 256 + lane * 4) = n1;
  if (lane == 0) {
    invd[row] = iv;
    invf[row] = (float)iv;
  }
}

// ------- prep: bf16-hi fragment-tiled + per-row norm (fused) ----------
__global__ __launch_bounds__(256) void k_prep(const float* __restrict__ src,
                                              unsigned short* __restrict__ hi,
                                              float* __restrict__ nrm) {
  const int tile = blockIdx.x;
  const int t = threadIdx.x;
  const int r = t >> 4;
  const int l16 = t & 15;
  const float4* s4 = (const float4*)(src + (size_t)tile * 16 * DDIM);
  double ss = 0.0;
  #pragma unroll
  for (int j = 0; j < 8; ++j) {
    const int f4 = r * 128 + l16 + j * 16;
    float4 v = s4[f4];
    ss += (double)v.x * v.x + (double)v.y * v.y + (double)v.z * v.z + (double)v.w * v.w;
    const int k = (l16 + j * 16) * 4;
    const int kc = k >> 5;
    const int l = r | (((k >> 3) & 3) << 4);
    ushort4 h4;
    h4.x = f2bf(v.x); h4.y = f2bf(v.y); h4.z = f2bf(v.z); h4.w = f2bf(v.w);
    *(ushort4*)(hi + (size_t)tile * 8192 + kc * 512 + l * 8 + (k & 7)) = h4;
  }
  #pragma unroll
  for (int m = 1; m < 16; m <<= 1) ss += __shfl_xor(ss, m);
  if (l16 == 0) nrm[tile * 16 + r] = (float)sqrt(ss);
}

// ---------------- MFMA scorer: 256x256 tile, hi-only, BK=32 ----------------
__global__ __launch_bounds__(512) void k_mfma(const unsigned short* __restrict__ AThi,
                                              const unsigned short* __restrict__ BThi,
                                              const float* __restrict__ invcf,
                                              const float* __restrict__ hnormf,
                                              float4* __restrict__ pcand,
                                              int* __restrict__ pt3) {
  __shared__ bf16x8 lds[4096];
  const int tx = threadIdx.x;
  const int bid = blockIdx.x;
  const int pr = (bid & 7) * 16 + (bid >> 5);
  const int pc = (bid >> 3) & 3;
  const int lane = tx & 63;
  const int wid = tx >> 6;
  const int wr = wid >> 1;
  const int wc = wid & 1;

  f32x4 acc[4][8];
  #pragma unroll
  for (int m = 0; m < 4; ++m)
    #pragma unroll
    for (int n = 0; n < 8; ++n) acc[m][n] = (f32x4)(0.0f);

  const int s0 = tx, s1 = tx + 512;
  const size_t a0 = (size_t)(pr * 16 + (s0 >> 6)) * 8192 + (s0 & 63) * 8;
  const size_t a1 = (size_t)(pr * 16 + (s1 >> 6)) * 8192 + (s1 & 63) * 8;
  const size_t b0 = (size_t)(pc * 16 + (s0 >> 6)) * 8192 + (s0 & 63) * 8;
  const size_t b1 = (size_t)(pc * 16 + (s1 >> 6)) * 8192 + (s1 & 63) * 8;

  gl16(AThi + a0, &lds[s0]);
  gl16(AThi + a1, &lds[s1]);
  gl16(BThi + b0, &lds[1024 + s0]);
  gl16(BThi + b1, &lds[1024 + s1]);
  __syncthreads();

  int cur = 0;
  for (int kc = 0; kc < 16; ++kc) {
    if (kc < 15) {
      const int off = (kc + 1) * 512;
      bf16x8* base = &lds[(cur ^ 1) * 2048];
      gl16(AThi + a0 + off, base + s0);
      gl16(AThi + a1 + off, base + s1);
      gl16(BThi + b0 + off, base + 1024 + s0);
      gl16(BThi + b1 + off, base + 1024 + s1);
    }
    const bf16x8* L = &lds[cur * 2048];
    bf16x8 af[4], bq[8];
    #pragma unroll
    for (int m = 0; m < 4; ++m) af[m] = L[(wr * 4 + m) * 64 + lane];
    #pragma unroll
    for (int n = 0; n < 8; ++n) bq[n] = L[1024 + (wc * 8 + n) * 64 + lane];
    #pragma unroll
    for (int m = 0; m < 4; ++m)
      #pragma unroll
      for (int n = 0; n < 8; ++n)
        acc[m][n] = __builtin_amdgcn_mfma_f32_16x16x32_bf16(af[m], bq[n], acc[m][n], 0, 0, 0);
    __syncthreads();
    cur ^= 1;
  }

  const int q = lane >> 4;
  const int c16 = lane & 15;
  const int rowbase = pr * 256 + wr * 64;

  #pragma unroll
  for (int hn = 0; hn < 2; ++hn) {
    const int colbase = pc * 256 + wc * 128 + hn * 64;
    const int st = colbase >> 6;
    float invn[4];
    #pragma unroll
    for (int n4 = 0; n4 < 4; ++n4) invn[n4] = invcf[colbase + n4 * 16 + c16];

    #pragma unroll
    for (int m = 0; m < 4; ++m) {
      #pragma unroll
      for (int r = 0; r < 4; ++r) {
        const int row = rowbase + m * 16 + q * 4 + r;
        float sv[4];
        #pragma unroll
        for (int n4 = 0; n4 < 4; ++n4) sv[n4] = acc[m][hn * 4 + n4][r] * invn[n4];

        // top1 (lowest index on ties)
        float t1 = sv[0]; int i1 = colbase + c16;
        #pragma unroll
        for (int n4 = 1; n4 < 4; ++n4) {
          const int idx = colbase + n4 * 16 + c16;
          if (sv[n4] > t1) { t1 = sv[n4]; i1 = idx; }
        }
        #pragma unroll
        for (int msk = 1; msk < 16; msk <<= 1) {
          float os = __shfl_xor(t1, msk); int oi = __shfl_xor(i1, msk);
          if (os > t1 || (os == t1 && oi < i1)) { t1 = os; i1 = oi; }
        }

        // top2 (best excluding i1)
        float t2 = -3.4e38f; int i2 = 0x7fffffff;
        #pragma unroll
        for (int n4 = 0; n4 < 4; ++n4) {
          const int idx = colbase + n4 * 16 + c16;
          if (idx != i1 && sv[n4] > t2) { t2 = sv[n4]; i2 = idx; }
        }
        #pragma unroll
        for (int msk = 1; msk < 16; msk <<= 1) {
          float os = __shfl_xor(t2, msk); int oi = __shfl_xor(i2, msk);
          if (os > t2 || (os == t2 && oi < i2)) { t2 = os; i2 = oi; }
        }

        // top3 VALUE (best excluding i1, i2) -- rescan trigger
        float t3 = -3.4e38f;
        #pragma unroll
        for (int n4 = 0; n4 < 4; ++n4) {
          const int idx = colbase + n4 * 16 + c16;
          if (idx != i1 && idx != i2 && sv[n4] > t3) t3 = sv[n4];
        }
        #pragma unroll
        for (int msk = 1; msk < 16; msk <<= 1)
          t3 = fmaxf(t3, __shfl_xor(t3, msk));

        if (c16 == 0) {
          pcand[(size_t)row * 16 + st] = make_float4(t1, __int_as_float(i1), t2, __int_as_float(i2));
          pt3[(size_t)row * 16 + st] = __float_as_int(t3);
        }
      }
    }
  }
}

// ---------------- select: one wave per row, fp64 exact argmax ----------------
__global__ __launch_bounds__(256) void k_select(const float* __restrict__ h,
                                                const float* __restrict__ cb,
                                                const double* __restrict__ invcd,
                                                const float* __restrict__ hnormf,
                                                const float4* __restrict__ pcand,
                                                const int* __restrict__ pt3,
                                                int* __restrict__ sidxb,
                                                float* __restrict__ out_idx) {
  const int lane = threadIdx.x & 63;
  const int row = blockIdx.x * 4 + (threadIdx.x >> 6);

  float4 pc4 = make_float4(-3.4e38f, 0.0f, -3.4e38f, 0.0f);
  float t3 = -3.4e38f;
  if (lane < 16) {
    pc4 = pcand[(size_t)row * 16 + lane];
    t3 = __int_as_float(pt3[(size_t)row * 16 + lane]);
  }
  float best = pc4.x;
  #pragma unroll
  for (int m = 1; m < 64; m <<= 1) best = fmaxf(best, __shfl_xor(best, m));
  const float thr = best - MARGIN_COEF * hnormf[row];

  const unsigned long long m1 = __ballot(pc4.x >= thr);
  const unsigned long long m2 = __ballot(pc4.z >= thr);
  const unsigned long long mr = __ballot(t3 >= thr);   // ~never fires

  // h row in registers (8 floats/lane)
  const float4* hp = (const float4*)(h + (size_t)row * DDIM + lane * 8);
  const float4 h0 = hp[0], h1 = hp[1];

  double bs = -1e300; int bi = 0x7fffffff;
  const int i1 = __float_as_int(pc4.y);
  const int i2 = __float_as_int(pc4.w);

  // candidate rescoring (fp64)
  #define RESCORE(codeexpr)                                                  \
    {                                                                        \
      const int code = (codeexpr);                                           \
      const float4* cp = (const float4*)(cb + (size_t)code * DDIM + lane*8); \
      const float4 c0 = cp[0], c1 = cp[1];                                   \
      double p = (double)h0.x * c0.x + (double)h0.y * c0.y                   \
               + (double)h0.z * c0.z + (double)h0.w * c0.w                   \
               + (double)h1.x * c1.x + (double)h1.y * c1.y                   \
               + (double)h1.z * c1.z + (double)h1.w * c1.w;                  \
      _Pragma("unroll")                                                      \
      for (int m = 1; m < 64; m <<= 1) p += __shfl_xor(p, m);                \
      const double sc = p * invcd[code];                                     \
      if (sc > bs || (sc == bs && code < bi)) { bs = sc; bi = code; }        \
    }

  for (unsigned long long mm = m1; mm; mm &= mm - 1)
    RESCORE(__shfl(i1, __builtin_ctzll(mm)));
  for (unsigned long long mm = m2; mm; mm &= mm - 1)
    RESCORE(__shfl(i2, __builtin_ctzll(mm)));
  for (unsigned long long mm = mr; mm; mm &= mm - 1) {
    const int st = __builtin_ctzll(mm);
    for (int j = 0; j < 64; ++j) RESCORE(st * 64 + j);
  }
  #undef RESCORE

  if (lane == 0) {
    sidxb[row] = bi;
    out_idx[row] = (float)bi;
  }
}

// ---------------- write: pure-bandwidth outputs + loss partials -------------
__global__ __launch_bounds__(256) void k_write(const float* __restrict__ h,
                                               const float* __restrict__ cbn,
                                               const int* __restrict__ sidxb,
                                               float* __restrict__ out_q,
                                               float* __restrict__ out_ct,
                                               float* __restrict__ out_ch,
                                               float* __restrict__ out_cq,
                                               double* __restrict__ lsum) {
  const int tx = threadIdx.x;
  const int r = blockIdx.x * 8 + (tx >> 5);
  const int g = tx & 31;
  const int bi = sidxb[r];

  {
    float* qrow = out_q + (size_t)r * KCODE;
    #pragma unroll
    for (int j = 0; j < 8; ++j) {
      const int col = g * 4 + j * 128;
      float4 qv;
      qv.x = (col + 0 == bi) ? 1.0f : 0.0f;
      qv.y = (col + 1 == bi) ? 1.0f : 0.0f;
      qv.z = (col + 2 == bi) ? 1.0f : 0.0f;
      qv.w = (col + 3 == bi) ? 1.0f : 0.0f;
      *(float4*)(qrow + col) = qv;
    }
  }

  float4 hvv[4], cvv[4];
  const float* hrow = h + (size_t)r * DDIM;
  const float* crow = cbn + (size_t)bi * DDIM;
  #pragma unroll
  for (int j = 0; j < 4; ++j) {
    const int col = g * 4 + j * 128;
    hvv[j] = *(const float4*)(hrow + col);
    cvv[j] = *(const float4*)(crow + col);
  }
  double hs = 0.0;
  #pragma unroll
  for (int j = 0; j < 4; ++j)
    hs += (double)hvv[j].x * hvv[j].x + (double)hvv[j].y * hvv[j].y
        + (double)hvv[j].z * hvv[j].z + (double)hvv[j].w * hvv[j].w;
  #pragma unroll
  for (int m = 1; m < 32; m <<= 1) hs += __shfl_xor(hs, m);
  const double ih = 1.0 / fmax(sqrt(hs), 1e-6);

  double ls = 0.0;
  #pragma unroll
  for (int j = 0; j < 4; ++j) {
    const int col = g * 4 + j * 128;
    const size_t ro = (size_t)r * DDIM + col;
    *(float4*)(out_ct + ro) = cvv[j];
    *(float4*)(out_ch + ro) = cvv[j];
    *(float4*)(out_cq + ro) = cvv[j];
    double e;
    e = (double)hvv[j].x * ih - (double)cvv[j].x; ls += e * e;
    e = (double)hvv[j].y * ih - (double)cvv[j].y; ls += e * e;
    e = (double)hvv[j].z * ih - (double)cvv[j].z; ls += e * e;
    e = (double)hvv[j].w * ih - (double)cvv[j].w; ls += e * e;
  }
  #pragma unroll
  for (int m = 1; m < 32; m <<= 1) ls += __shfl_xor(ls, m);
  if (g == 0) lsum[r] = ls;
}

__global__ __launch_bounds__(256) void k_loss(const double* __restrict__ lsum,
                                              float* __restrict__ out_loss) {
  const int tx = threadIdx.x;
  double s = 0.0;
  for (int i = tx; i < NROWS; i += 256) s += lsum[i];
  #pragma unroll
  for (int m = 1; m < 64; m <<= 1) s += __shfl_xor(s, m);
  __shared__ double sh[4];
  if ((tx & 63) == 0) sh[tx >> 6] = s;
  __syncthreads();
  if (tx == 0)
    out_loss[0] = (float)(1.25 * (sh[0] + sh[1] + sh[2] + sh[3]) / ((double)NROWS * (double)DDIM));
}

extern "C" void kernel_launch(void* const* d_in, const int* in_sizes, int n_in,
                              void* d_out, int out_size, void* d_ws, size_t ws_size,
                              hipStream_t stream) {
  const float* h = (const float*)d_in[0];
  const float* cb = (const float*)d_in[1];

  float* out = (float*)d_out;
  float* out_q    = out;
  float* out_ct   = out + 33554432;
  float* out_ch   = out + 50331648;
  float* out_cq   = out + 67108864;
  float* out_loss = out + 83886080;
  float* out_idx  = out + 83886081;

  char* ws = (char*)d_ws;
  unsigned short* AThi = (unsigned short*)(ws);               // 32 MB
  unsigned short* BThi = (unsigned short*)(ws + 33554432);    // 1 MB
  double* invcd  = (double*)(ws + 34603008);                  // 8 KB
  float*  invcf  = (float*)(ws + 34611200);                   // 4 KB
  float*  hnormf = (float*)(ws + 34615296);                   // 128 KB
  float*  cbnrm  = (float*)(ws + 34746368);                   // 4 KB (sink)
  float*  cbn    = (float*)(ws + 34750464);                   // 2 MB
  float4* pcand  = (float4*)(ws + 36847616);                  // 8 MB
  int*    pt3    = (int*)(ws + 45236224);                     // 2 MB
  double* lsum   = (double*)(ws + 47333376);                  // 256 KB
  int*    sidxb  = (int*)(ws + 47595520);                     // 128 KB

  k_invc<<<KCODE / 4, 256, 0, stream>>>(cb, invcd, invcf, cbn);
  k_prep<<<NROWS / 16, 256, 0, stream>>>(h, AThi, hnormf);
  k_prep<<<KCODE / 16, 256, 0, stream>>>(cb, BThi, cbnrm);
  k_mfma<<<512, 512, 0, stream>>>(AThi, BThi, invcf, hnormf, pcand, pt3);
  k_select<<<NROWS / 4, 256, 0, stream>>>(h, cb, invcd, hnormf, pcand, pt3,
                                          sidxb, out_idx);
  k_write<<<NROWS / 8, 256, 0, stream>>>(h, cbn, sidxb,
                                         out_q, out_ct, out_ch, out_cq, lsum);
  k_loss<<<1, 256, 0, stream>>>(lsum, out_loss);
}

// Round 10
// 307.330 us; speedup vs baseline: 1.1630x; 1.0322x over previous
//
#include <hip/hip_runtime.h>
#include <math.h>

// VQQuantizer eval, round 10.
// Round 8 exactness machinery unchanged (hi-only bf16 MFMA + margin
// 0.017*||h|| + t3 rescan trigger + fp64 rescore + t3-triggered rescan).
// k_mfma: 128x128 tile, 4 waves, acc[4][4], double-buffered LDS (32 KB) with
// plain __syncthreads() per chunk (compiler-inserted vmcnt/lgkm drains --
// the structure proven correct in rounds 5/6). Occupancy ~4 blocks/CU makes
// cross-block wave overlap hide the per-chunk drain (round-9's hand-rolled
// counted-vmcnt pipeline raced; reverted).

#define NROWS 32768
#define DDIM  512
#define KCODE 1024
#define MARGIN_COEF 0.017f

typedef __attribute__((address_space(1))) const void gvoid_t;
typedef __attribute__((address_space(3))) void svoid_t;
typedef float f32x4 __attribute__((ext_vector_type(4)));
typedef short bf16x8 __attribute__((ext_vector_type(8)));

__device__ __forceinline__ void gl16(const void* g, void* s) {
  __builtin_amdgcn_global_load_lds((gvoid_t*)g, (svoid_t*)s, 16, 0, 0);
}
// round-to-nearest-even f32 -> bf16 (finite inputs only)
__device__ __forceinline__ unsigned short f2bf(float x) {
  unsigned u = __float_as_uint(x);
  u = u + 0x7fffu + ((u >> 16) & 1u);
  return (unsigned short)(u >> 16);
}

// ------ codebook inverse norms + normalized codebook (f32 of fp64 math) -----
__global__ __launch_bounds__(256) void k_invc(const float* __restrict__ x,
                                              double* __restrict__ invd,
                                              float* __restrict__ invf,
                                              float* __restrict__ cbn) {
  const int lane = threadIdx.x & 63;
  const int row = blockIdx.x * 4 + (threadIdx.x >> 6);
  const float* p = x + (size_t)row * DDIM;
  float4 v0 = *(const float4*)(p + lane * 4);
  float4 v1 = *(const float4*)(p + 256 + lane * 4);
  double s = (double)v0.x * v0.x + (double)v0.y * v0.y + (double)v0.z * v0.z + (double)v0.w * v0.w
           + (double)v1.x * v1.x + (double)v1.y * v1.y + (double)v1.z * v1.z + (double)v1.w * v1.w;
  #pragma unroll
  for (int m = 1; m < 64; m <<= 1) s += __shfl_xor(s, m);
  const double iv = 1.0 / fmax(sqrt(s), 1e-6);
  float4 n0, n1;
  n0.x = (float)((double)v0.x * iv); n0.y = (float)((double)v0.y * iv);
  n0.z = (float)((double)v0.z * iv); n0.w = (float)((double)v0.w * iv);
  n1.x = (float)((double)v1.x * iv); n1.y = (float)((double)v1.y * iv);
  n1.z = (float)((double)v1.z * iv); n1.w = (float)((double)v1.w * iv);
  *(float4*)(cbn + (size_t)row * DDIM + lane * 4) = n0;
  *(float4*)(cbn + (size_t)row * DDIM + 256 + lane * 4) = n1;
  if (lane == 0) {
    invd[row] = iv;
    invf[row] = (float)iv;
  }
}

// ------- prep: bf16-hi fragment-tiled + per-row norm (fused) ----------
__global__ __launch_bounds__(256) void k_prep(const float* __restrict__ src,
                                              unsigned short* __restrict__ hi,
                                              float* __restrict__ nrm) {
  const int tile = blockIdx.x;
  const int t = threadIdx.x;
  const int r = t >> 4;
  const int l16 = t & 15;
  const float4* s4 = (const float4*)(src + (size_t)tile * 16 * DDIM);
  double ss = 0.0;
  #pragma unroll
  for (int j = 0; j < 8; ++j) {
    const int f4 = r * 128 + l16 + j * 16;
    float4 v = s4[f4];
    ss += (double)v.x * v.x + (double)v.y * v.y + (double)v.z * v.z + (double)v.w * v.w;
    const int k = (l16 + j * 16) * 4;
    const int kc = k >> 5;
    const int l = r | (((k >> 3) & 3) << 4);
    ushort4 h4;
    h4.x = f2bf(v.x); h4.y = f2bf(v.y); h4.z = f2bf(v.z); h4.w = f2bf(v.w);
    *(ushort4*)(hi + (size_t)tile * 8192 + kc * 512 + l * 8 + (k & 7)) = h4;
  }
  #pragma unroll
  for (int m = 1; m < 16; m <<= 1) ss += __shfl_xor(ss, m);
  if (l16 == 0) nrm[tile * 16 + r] = (float)sqrt(ss);
}

// -------- MFMA scorer: 128x128 tile, hi-only, BK=32, dbuf + syncthreads ----
// Swizzle: pr=(bid&7)*32+(bid>>6), pc=(bid>>3)&7 (bijective over 2048);
// XCD = bid%8 -> the 8 pc-blocks of each pr are consecutive on one XCD.
__global__ __launch_bounds__(256) void k_mfma(const unsigned short* __restrict__ AThi,
                                              const unsigned short* __restrict__ BThi,
                                              const float* __restrict__ invcf,
                                              const float* __restrict__ hnormf,
                                              float4* __restrict__ pcand,
                                              int* __restrict__ pt3) {
  __shared__ bf16x8 lds[2048];   // 2 bufs x {A 512, B 512} slots = 32 KB
  const int tx = threadIdx.x;
  const int bid = blockIdx.x;
  const int pr = (bid & 7) * 32 + (bid >> 6);
  const int pc = (bid >> 3) & 7;
  const int lane = tx & 63;
  const int wid = tx >> 6;
  const int wr = wid >> 1, wc = wid & 1;

  f32x4 acc[4][4];
  #pragma unroll
  for (int m = 0; m < 4; ++m)
    #pragma unroll
    for (int n = 0; n < 4; ++n) acc[m][n] = (f32x4)(0.0f);

  // staging: wave wid stages A subtiles {wid, wid+4}, B subtiles {wid, wid+4}
  const size_t aA0 = (size_t)(pr * 8 + wid) * 8192 + lane * 8;
  const size_t aA1 = (size_t)(pr * 8 + wid + 4) * 8192 + lane * 8;
  const size_t aB0 = (size_t)(pc * 8 + wid) * 8192 + lane * 8;
  const size_t aB1 = (size_t)(pc * 8 + wid + 4) * 8192 + lane * 8;
  const int slA0 = wid * 64 + lane;
  const int slA1 = (wid + 4) * 64 + lane;
  const int slB0 = 512 + wid * 64 + lane;
  const int slB1 = 512 + (wid + 4) * 64 + lane;

#define STAGE(bufi, kcc)                                   \
  {                                                        \
    bf16x8* base = &lds[(bufi) * 1024];                    \
    const int o_ = (kcc) * 512;                            \
    gl16(AThi + aA0 + o_, base + slA0);                    \
    gl16(AThi + aA1 + o_, base + slA1);                    \
    gl16(BThi + aB0 + o_, base + slB0);                    \
    gl16(BThi + aB1 + o_, base + slB1);                    \
  }

  STAGE(0, 0);
  __syncthreads();   // chunk 0 landed (compiler drains vmcnt before barrier)

  for (int kc = 0; kc < 16; ++kc) {
    if (kc < 15) STAGE((kc + 1) & 1, kc + 1);   // prefetch next chunk
    const bf16x8* L = &lds[(kc & 1) * 1024];
    bf16x8 af[4], bq[4];
    #pragma unroll
    for (int m = 0; m < 4; ++m) af[m] = L[(wr * 4 + m) * 64 + lane];
    #pragma unroll
    for (int n = 0; n < 4; ++n) bq[n] = L[512 + (wc * 4 + n) * 64 + lane];
    #pragma unroll
    for (int m = 0; m < 4; ++m)
      #pragma unroll
      for (int n = 0; n < 4; ++n)
        acc[m][n] = __builtin_amdgcn_mfma_f32_16x16x32_bf16(af[m], bq[n], acc[m][n], 0, 0, 0);
    __syncthreads();   // prefetch landed + all waves done reading this buf
  }
#undef STAGE

  // ---- epilogue: per-row top1/top2/t3 over this wave's 64-col stripe ----
  const int q = lane >> 4;
  const int c16 = lane & 15;
  const int rowbase = pr * 128 + wr * 64;
  const int colbase = pc * 128 + wc * 64;
  const int st = colbase >> 6;

  float invn[4];
  #pragma unroll
  for (int n4 = 0; n4 < 4; ++n4) invn[n4] = invcf[colbase + n4 * 16 + c16];

  #pragma unroll
  for (int m = 0; m < 4; ++m) {
    #pragma unroll
    for (int r = 0; r < 4; ++r) {
      const int row = rowbase + m * 16 + q * 4 + r;
      float sv[4];
      #pragma unroll
      for (int n4 = 0; n4 < 4; ++n4) sv[n4] = acc[m][n4][r] * invn[n4];

      // top1 (lowest index on ties)
      float t1 = sv[0]; int i1 = colbase + c16;
      #pragma unroll
      for (int n4 = 1; n4 < 4; ++n4) {
        const int idx = colbase + n4 * 16 + c16;
        if (sv[n4] > t1) { t1 = sv[n4]; i1 = idx; }
      }
      #pragma unroll
      for (int msk = 1; msk < 16; msk <<= 1) {
        float os = __shfl_xor(t1, msk); int oi = __shfl_xor(i1, msk);
        if (os > t1 || (os == t1 && oi < i1)) { t1 = os; i1 = oi; }
      }

      // top2 (best excluding i1)
      float t2 = -3.4e38f; int i2 = 0x7fffffff;
      #pragma unroll
      for (int n4 = 0; n4 < 4; ++n4) {
        const int idx = colbase + n4 * 16 + c16;
        if (idx != i1 && sv[n4] > t2) { t2 = sv[n4]; i2 = idx; }
      }
      #pragma unroll
      for (int msk = 1; msk < 16; msk <<= 1) {
        float os = __shfl_xor(t2, msk); int oi = __shfl_xor(i2, msk);
        if (os > t2 || (os == t2 && oi < i2)) { t2 = os; i2 = oi; }
      }

      // top3 VALUE (rescan trigger)
      float t3 = -3.4e38f;
      #pragma unroll
      for (int n4 = 0; n4 < 4; ++n4) {
        const int idx = colbase + n4 * 16 + c16;
        if (idx != i1 && idx != i2 && sv[n4] > t3) t3 = sv[n4];
      }
      #pragma unroll
      for (int msk = 1; msk < 16; msk <<= 1)
        t3 = fmaxf(t3, __shfl_xor(t3, msk));

      if (c16 == 0) {
        pcand[(size_t)row * 16 + st] = make_float4(t1, __int_as_float(i1), t2, __int_as_float(i2));
        pt3[(size_t)row * 16 + st] = __float_as_int(t3);
      }
    }
  }
}

// ---------------- select: one wave per row, fp64 exact argmax ----------------
__global__ __launch_bounds__(256) void k_select(const float* __restrict__ h,
                                                const float* __restrict__ cb,
                                                const double* __restrict__ invcd,
                                                const float* __restrict__ hnormf,
                                                const float4* __restrict__ pcand,
                                                const int* __restrict__ pt3,
                                                int* __restrict__ sidxb,
                                                float* __restrict__ out_idx) {
  const int lane = threadIdx.x & 63;
  const int row = blockIdx.x * 4 + (threadIdx.x >> 6);

  float4 pc4 = make_float4(-3.4e38f, 0.0f, -3.4e38f, 0.0f);
  float t3 = -3.4e38f;
  if (lane < 16) {
    pc4 = pcand[(size_t)row * 16 + lane];
    t3 = __int_as_float(pt3[(size_t)row * 16 + lane]);
  }
  float best = pc4.x;
  #pragma unroll
  for (int m = 1; m < 64; m <<= 1) best = fmaxf(best, __shfl_xor(best, m));
  const float thr = best - MARGIN_COEF * hnormf[row];

  const unsigned long long m1 = __ballot(pc4.x >= thr);
  const unsigned long long m2 = __ballot(pc4.z >= thr);
  const unsigned long long mr = __ballot(t3 >= thr);   // ~never fires

  const float4* hp = (const float4*)(h + (size_t)row * DDIM + lane * 8);
  const float4 h0 = hp[0], h1 = hp[1];

  double bs = -1e300; int bi = 0x7fffffff;
  const int i1 = __float_as_int(pc4.y);
  const int i2 = __float_as_int(pc4.w);

  #define RESCORE(codeexpr)                                                  \
    {                                                                        \
      const int code = (codeexpr);                                           \
      const float4* cp = (const float4*)(cb + (size_t)code * DDIM + lane*8); \
      const float4 c0 = cp[0], c1 = cp[1];                                   \
      double p = (double)h0.x * c0.x + (double)h0.y * c0.y                   \
               + (double)h0.z * c0.z + (double)h0.w * c0.w                   \
               + (double)h1.x * c1.x + (double)h1.y * c1.y                   \
               + (double)h1.z * c1.z + (double)h1.w * c1.w;                  \
      _Pragma("unroll")                                                      \
      for (int m = 1; m < 64; m <<= 1) p += __shfl_xor(p, m);                \
      const double sc = p * invcd[code];                                     \
      if (sc > bs || (sc == bs && code < bi)) { bs = sc; bi = code; }        \
    }

  for (unsigned long long mm = m1; mm; mm &= mm - 1)
    RESCORE(__shfl(i1, __builtin_ctzll(mm)));
  for (unsigned long long mm = m2; mm; mm &= mm - 1)
    RESCORE(__shfl(i2, __builtin_ctzll(mm)));
  for (unsigned long long mm = mr; mm; mm &= mm - 1) {
    const int st = __builtin_ctzll(mm);
    for (int j = 0; j < 64; ++j) RESCORE(st * 64 + j);
  }
  #undef RESCORE

  if (lane == 0) {
    sidxb[row] = bi;
    out_idx[row] = (float)bi;
  }
}

// ---------------- write: pure-bandwidth outputs + loss partials -------------
__global__ __launch_bounds__(256) void k_write(const float* __restrict__ h,
                                               const float* __restrict__ cbn,
                                               const int* __restrict__ sidxb,
                                               float* __restrict__ out_q,
                                               float* __restrict__ out_ct,
                                               float* __restrict__ out_ch,
                                               float* __restrict__ out_cq,
                                               double* __restrict__ lsum) {
  const int tx = threadIdx.x;
  const int r = blockIdx.x * 8 + (tx >> 5);
  const int g = tx & 31;
  const int bi = sidxb[r];

  {
    float* qrow = out_q + (size_t)r * KCODE;
    #pragma unroll
    for (int j = 0; j < 8; ++j) {
      const int col = g * 4 + j * 128;
      float4 qv;
      qv.x = (col + 0 == bi) ? 1.0f : 0.0f;
      qv.y = (col + 1 == bi) ? 1.0f : 0.0f;
      qv.z = (col + 2 == bi) ? 1.0f : 0.0f;
      qv.w = (col + 3 == bi) ? 1.0f : 0.0f;
      *(float4*)(qrow + col) = qv;
    }
  }

  float4 hvv[4], cvv[4];
  const float* hrow = h + (size_t)r * DDIM;
  const float* crow = cbn + (size_t)bi * DDIM;
  #pragma unroll
  for (int j = 0; j < 4; ++j) {
    const int col = g * 4 + j * 128;
    hvv[j] = *(const float4*)(hrow + col);
    cvv[j] = *(const float4*)(crow + col);
  }
  double hs = 0.0;
  #pragma unroll
  for (int j = 0; j < 4; ++j)
    hs += (double)hvv[j].x * hvv[j].x + (double)hvv[j].y * hvv[j].y
        + (double)hvv[j].z * hvv[j].z + (double)hvv[j].w * hvv[j].w;
  #pragma unroll
  for (int m = 1; m < 32; m <<= 1) hs += __shfl_xor(hs, m);
  const double ih = 1.0 / fmax(sqrt(hs), 1e-6);

  double ls = 0.0;
  #pragma unroll
  for (int j = 0; j < 4; ++j) {
    const int col = g * 4 + j * 128;
    const size_t ro = (size_t)r * DDIM + col;
    *(float4*)(out_ct + ro) = cvv[j];
    *(float4*)(out_ch + ro) = cvv[j];
    *(float4*)(out_cq + ro) = cvv[j];
    double e;
    e = (double)hvv[j].x * ih - (double)cvv[j].x; ls += e * e;
    e = (double)hvv[j].y * ih - (double)cvv[j].y; ls += e * e;
    e = (double)hvv[j].z * ih - (double)cvv[j].z; ls += e * e;
    e = (double)hvv[j].w * ih - (double)cvv[j].w; ls += e * e;
  }
  #pragma unroll
  for (int m = 1; m < 32; m <<= 1) ls += __shfl_xor(ls, m);
  if (g == 0) lsum[r] = ls;
}

__global__ __launch_bounds__(256) void k_loss(const double* __restrict__ lsum,
                                              float* __restrict__ out_loss) {
  const int tx = threadIdx.x;
  double s = 0.0;
  for (int i = tx; i < NROWS; i += 256) s += lsum[i];
  #pragma unroll
  for (int m = 1; m < 64; m <<= 1) s += __shfl_xor(s, m);
  __shared__ double sh[4];
  if ((tx & 63) == 0) sh[tx >> 6] = s;
  __syncthreads();
  if (tx == 0)
    out_loss[0] = (float)(1.25 * (sh[0] + sh[1] + sh[2] + sh[3]) / ((double)NROWS * (double)DDIM));
}

extern "C" void kernel_launch(void* const* d_in, const int* in_sizes, int n_in,
                              void* d_out, int out_size, void* d_ws, size_t ws_size,
                              hipStream_t stream) {
  const float* h = (const float*)d_in[0];
  const float* cb = (const float*)d_in[1];

  float* out = (float*)d_out;
  float* out_q    = out;
  float* out_ct   = out + 33554432;
  float* out_ch   = out + 50331648;
  float* out_cq   = out + 67108864;
  float* out_loss = out + 83886080;
  float* out_idx  = out + 83886081;

  char* ws = (char*)d_ws;
  unsigned short* AThi = (unsigned short*)(ws);               // 32 MB
  unsigned short* BThi = (unsigned short*)(ws + 33554432);    // 1 MB
  double* invcd  = (double*)(ws + 34603008);                  // 8 KB
  float*  invcf  = (float*)(ws + 34611200);                   // 4 KB
  float*  hnormf = (float*)(ws + 34615296);                   // 128 KB
  float*  cbnrm  = (float*)(ws + 34746368);                   // 4 KB (sink)
  float*  cbn    = (float*)(ws + 34750464);                   // 2 MB
  float4* pcand  = (float4*)(ws + 36847616);                  // 8 MB
  int*    pt3    = (int*)(ws + 45236224);                     // 2 MB
  double* lsum   = (double*)(ws + 47333376);                  // 256 KB
  int*    sidxb  = (int*)(ws + 47595520);                     // 128 KB

  k_invc<<<KCODE / 4, 256, 0, stream>>>(cb, invcd, invcf, cbn);
  k_prep<<<NROWS / 16, 256, 0, stream>>>(h, AThi, hnormf);
  k_prep<<<KCODE / 16, 256, 0, stream>>>(cb, BThi, cbnrm);
  k_mfma<<<2048, 256, 0, stream>>>(AThi, BThi, invcf, hnormf, pcand, pt3);
  k_select<<<NROWS / 4, 256, 0, stream>>>(h, cb, invcd, hnormf, pcand, pt3,
                                          sidxb, out_idx);
  k_write<<<NROWS / 8, 256, 0, stream>>>(h, cbn, sidxb,
                                         out_q, out_ct, out_ch, out_cq, lsum);
  k_loss<<<1, 256, 0, stream>>>(lsum, out_loss);
}

// Round 12
// 274.120 us; speedup vs baseline: 1.3039x; 1.1211x over previous
//
#include <hip/hip_runtime.h>
#include <math.h>

// VQQuantizer eval, round 12 = round 11 with nontemporal stores fixed
// (__builtin_nontemporal_store requires clang ext_vector types, not
// HIP_vector_type float4 -- use f32x4 throughout k_selwrite).
// Exactness machinery unchanged (hi-only bf16 MFMA scorer, margin 0.017*||h||,
// per-stripe top1/top2 + t3 rescan trigger, fp64 candidate rescoring).

#define NROWS 32768
#define DDIM  512
#define KCODE 1024
#define MARGIN_COEF 0.017f

typedef __attribute__((address_space(1))) const void gvoid_t;
typedef __attribute__((address_space(3))) void svoid_t;
typedef float f32x4 __attribute__((ext_vector_type(4)));
typedef short bf16x8 __attribute__((ext_vector_type(8)));

__device__ __forceinline__ void gl16(const void* g, void* s) {
  __builtin_amdgcn_global_load_lds((gvoid_t*)g, (svoid_t*)s, 16, 0, 0);
}
// round-to-nearest-even f32 -> bf16 (finite inputs only)
__device__ __forceinline__ unsigned short f2bf(float x) {
  unsigned u = __float_as_uint(x);
  u = u + 0x7fffu + ((u >> 16) & 1u);
  return (unsigned short)(u >> 16);
}

// ------ codebook inverse norms + normalized codebook (f32 of fp64 math) -----
__global__ __launch_bounds__(256) void k_invc(const float* __restrict__ x,
                                              double* __restrict__ invd,
                                              float* __restrict__ invf,
                                              float* __restrict__ cbn) {
  const int lane = threadIdx.x & 63;
  const int row = blockIdx.x * 4 + (threadIdx.x >> 6);
  const float* p = x + (size_t)row * DDIM;
  float4 v0 = *(const float4*)(p + lane * 4);
  float4 v1 = *(const float4*)(p + 256 + lane * 4);
  double s = (double)v0.x * v0.x + (double)v0.y * v0.y + (double)v0.z * v0.z + (double)v0.w * v0.w
           + (double)v1.x * v1.x + (double)v1.y * v1.y + (double)v1.z * v1.z + (double)v1.w * v1.w;
  #pragma unroll
  for (int m = 1; m < 64; m <<= 1) s += __shfl_xor(s, m);
  const double iv = 1.0 / fmax(sqrt(s), 1e-6);
  float4 n0, n1;
  n0.x = (float)((double)v0.x * iv); n0.y = (float)((double)v0.y * iv);
  n0.z = (float)((double)v0.z * iv); n0.w = (float)((double)v0.w * iv);
  n1.x = (float)((double)v1.x * iv); n1.y = (float)((double)v1.y * iv);
  n1.z = (float)((double)v1.z * iv); n1.w = (float)((double)v1.w * iv);
  *(float4*)(cbn + (size_t)row * DDIM + lane * 4) = n0;
  *(float4*)(cbn + (size_t)row * DDIM + 256 + lane * 4) = n1;
  if (lane == 0) {
    invd[row] = iv;
    invf[row] = (float)iv;
  }
}

// ------- prep: bf16-hi fragment-tiled + per-row norm (f32 + f64) ----------
__global__ __launch_bounds__(256) void k_prep(const float* __restrict__ src,
                                              unsigned short* __restrict__ hi,
                                              float* __restrict__ nrmf,
                                              double* __restrict__ nrmd) {
  const int tile = blockIdx.x;
  const int t = threadIdx.x;
  const int r = t >> 4;
  const int l16 = t & 15;
  const float4* s4 = (const float4*)(src + (size_t)tile * 16 * DDIM);
  double ss = 0.0;
  #pragma unroll
  for (int j = 0; j < 8; ++j) {
    const int f4 = r * 128 + l16 + j * 16;
    float4 v = s4[f4];
    ss += (double)v.x * v.x + (double)v.y * v.y + (double)v.z * v.z + (double)v.w * v.w;
    const int k = (l16 + j * 16) * 4;
    const int kc = k >> 5;
    const int l = r | (((k >> 3) & 3) << 4);
    ushort4 h4;
    h4.x = f2bf(v.x); h4.y = f2bf(v.y); h4.z = f2bf(v.z); h4.w = f2bf(v.w);
    *(ushort4*)(hi + (size_t)tile * 8192 + kc * 512 + l * 8 + (k & 7)) = h4;
  }
  #pragma unroll
  for (int m = 1; m < 16; m <<= 1) ss += __shfl_xor(ss, m);
  if (l16 == 0) {
    const double nd = sqrt(ss);
    nrmf[tile * 16 + r] = (float)nd;
    nrmd[tile * 16 + r] = nd;
  }
}

// -------- MFMA scorer: 128x128 tile, hi-only, BK=32, dbuf + syncthreads ----
// (unchanged from round 10 -- passed)
__global__ __launch_bounds__(256) void k_mfma(const unsigned short* __restrict__ AThi,
                                              const unsigned short* __restrict__ BThi,
                                              const float* __restrict__ invcf,
                                              const float* __restrict__ hnormf,
                                              float4* __restrict__ pcand,
                                              int* __restrict__ pt3) {
  __shared__ bf16x8 lds[2048];   // 2 bufs x {A 512, B 512} slots = 32 KB
  const int tx = threadIdx.x;
  const int bid = blockIdx.x;
  const int pr = (bid & 7) * 32 + (bid >> 6);
  const int pc = (bid >> 3) & 7;
  const int lane = tx & 63;
  const int wid = tx >> 6;
  const int wr = wid >> 1, wc = wid & 1;

  f32x4 acc[4][4];
  #pragma unroll
  for (int m = 0; m < 4; ++m)
    #pragma unroll
    for (int n = 0; n < 4; ++n) acc[m][n] = (f32x4)(0.0f);

  const size_t aA0 = (size_t)(pr * 8 + wid) * 8192 + lane * 8;
  const size_t aA1 = (size_t)(pr * 8 + wid + 4) * 8192 + lane * 8;
  const size_t aB0 = (size_t)(pc * 8 + wid) * 8192 + lane * 8;
  const size_t aB1 = (size_t)(pc * 8 + wid + 4) * 8192 + lane * 8;
  const int slA0 = wid * 64 + lane;
  const int slA1 = (wid + 4) * 64 + lane;
  const int slB0 = 512 + wid * 64 + lane;
  const int slB1 = 512 + (wid + 4) * 64 + lane;

#define STAGE(bufi, kcc)                                   \
  {                                                        \
    bf16x8* base = &lds[(bufi) * 1024];                    \
    const int o_ = (kcc) * 512;                            \
    gl16(AThi + aA0 + o_, base + slA0);                    \
    gl16(AThi + aA1 + o_, base + slA1);                    \
    gl16(BThi + aB0 + o_, base + slB0);                    \
    gl16(BThi + aB1 + o_, base + slB1);                    \
  }

  STAGE(0, 0);
  __syncthreads();

  for (int kc = 0; kc < 16; ++kc) {
    if (kc < 15) STAGE((kc + 1) & 1, kc + 1);
    const bf16x8* L = &lds[(kc & 1) * 1024];
    bf16x8 af[4], bq[4];
    #pragma unroll
    for (int m = 0; m < 4; ++m) af[m] = L[(wr * 4 + m) * 64 + lane];
    #pragma unroll
    for (int n = 0; n < 4; ++n) bq[n] = L[512 + (wc * 4 + n) * 64 + lane];
    #pragma unroll
    for (int m = 0; m < 4; ++m)
      #pragma unroll
      for (int n = 0; n < 4; ++n)
        acc[m][n] = __builtin_amdgcn_mfma_f32_16x16x32_bf16(af[m], bq[n], acc[m][n], 0, 0, 0);
    __syncthreads();
  }
#undef STAGE

  const int q = lane >> 4;
  const int c16 = lane & 15;
  const int rowbase = pr * 128 + wr * 64;
  const int colbase = pc * 128 + wc * 64;
  const int st = colbase >> 6;

  float invn[4];
  #pragma unroll
  for (int n4 = 0; n4 < 4; ++n4) invn[n4] = invcf[colbase + n4 * 16 + c16];

  #pragma unroll
  for (int m = 0; m < 4; ++m) {
    #pragma unroll
    for (int r = 0; r < 4; ++r) {
      const int row = rowbase + m * 16 + q * 4 + r;
      float sv[4];
      #pragma unroll
      for (int n4 = 0; n4 < 4; ++n4) sv[n4] = acc[m][n4][r] * invn[n4];

      float t1 = sv[0]; int i1 = colbase + c16;
      #pragma unroll
      for (int n4 = 1; n4 < 4; ++n4) {
        const int idx = colbase + n4 * 16 + c16;
        if (sv[n4] > t1) { t1 = sv[n4]; i1 = idx; }
      }
      #pragma unroll
      for (int msk = 1; msk < 16; msk <<= 1) {
        float os = __shfl_xor(t1, msk); int oi = __shfl_xor(i1, msk);
        if (os > t1 || (os == t1 && oi < i1)) { t1 = os; i1 = oi; }
      }

      float t2 = -3.4e38f; int i2 = 0x7fffffff;
      #pragma unroll
      for (int n4 = 0; n4 < 4; ++n4) {
        const int idx = colbase + n4 * 16 + c16;
        if (idx != i1 && sv[n4] > t2) { t2 = sv[n4]; i2 = idx; }
      }
      #pragma unroll
      for (int msk = 1; msk < 16; msk <<= 1) {
        float os = __shfl_xor(t2, msk); int oi = __shfl_xor(i2, msk);
        if (os > t2 || (os == t2 && oi < i2)) { t2 = os; i2 = oi; }
      }

      float t3 = -3.4e38f;
      #pragma unroll
      for (int n4 = 0; n4 < 4; ++n4) {
        const int idx = colbase + n4 * 16 + c16;
        if (idx != i1 && idx != i2 && sv[n4] > t3) t3 = sv[n4];
      }
      #pragma unroll
      for (int msk = 1; msk < 16; msk <<= 1)
        t3 = fmaxf(t3, __shfl_xor(t3, msk));

      if (c16 == 0) {
        pcand[(size_t)row * 16 + st] = make_float4(t1, __int_as_float(i1), t2, __int_as_float(i2));
        pt3[(size_t)row * 16 + st] = __float_as_int(t3);
      }
    }
  }
}

// ------ fused select+write: one wave per row ------
// Phase 1 (select): ballot candidate build, fp64 rescoring, exact argmax.
// Phase 2 (write): q one-hot + ct/ch/cq (= cbn[bi]) + fp64 loss partial,
// nontemporal stores (f32x4 ext_vectors). h loaded once, kept in registers.
__global__ __launch_bounds__(256) void k_selwrite(const float* __restrict__ h,
                                                  const float* __restrict__ cb,
                                                  const float* __restrict__ cbn,
                                                  const double* __restrict__ invcd,
                                                  const double* __restrict__ hnormd,
                                                  const float* __restrict__ hnormf,
                                                  const float4* __restrict__ pcand,
                                                  const int* __restrict__ pt3,
                                                  float* __restrict__ out_q,
                                                  float* __restrict__ out_ct,
                                                  float* __restrict__ out_ch,
                                                  float* __restrict__ out_cq,
                                                  float* __restrict__ out_idx,
                                                  double* __restrict__ lsum) {
  const int lane = threadIdx.x & 63;
  const int row = blockIdx.x * 4 + (threadIdx.x >> 6);

  // ---- phase 1: candidate build + fp64 rescore ----
  float4 pc4 = make_float4(-3.4e38f, 0.0f, -3.4e38f, 0.0f);
  float t3 = -3.4e38f;
  if (lane < 16) {
    pc4 = pcand[(size_t)row * 16 + lane];
    t3 = __int_as_float(pt3[(size_t)row * 16 + lane]);
  }
  float best = pc4.x;
  #pragma unroll
  for (int m = 1; m < 64; m <<= 1) best = fmaxf(best, __shfl_xor(best, m));
  const float thr = best - MARGIN_COEF * hnormf[row];

  const unsigned long long m1 = __ballot(pc4.x >= thr);
  const unsigned long long m2 = __ballot(pc4.z >= thr);
  const unsigned long long mr = __ballot(t3 >= thr);   // ~never fires

  // h row at write-pass layout: lane*4 and 256+lane*4
  const float* hrow = h + (size_t)row * DDIM;
  const f32x4 h0 = *(const f32x4*)(hrow + lane * 4);
  const f32x4 h1 = *(const f32x4*)(hrow + 256 + lane * 4);

  double bs = -1e300; int bi = 0x7fffffff;
  const int i1 = __float_as_int(pc4.y);
  const int i2 = __float_as_int(pc4.w);

  #define RESCORE(codeexpr)                                                   \
    {                                                                         \
      const int code = (codeexpr);                                            \
      const float* cp = cb + (size_t)code * DDIM;                             \
      const f32x4 c0 = *(const f32x4*)(cp + lane * 4);                        \
      const f32x4 c1 = *(const f32x4*)(cp + 256 + lane * 4);                  \
      double p = (double)h0.x * c0.x + (double)h0.y * c0.y                    \
               + (double)h0.z * c0.z + (double)h0.w * c0.w                    \
               + (double)h1.x * c1.x + (double)h1.y * c1.y                    \
               + (double)h1.z * c1.z + (double)h1.w * c1.w;                   \
      _Pragma("unroll")                                                       \
      for (int m = 1; m < 64; m <<= 1) p += __shfl_xor(p, m);                 \
      const double sc = p * invcd[code];                                      \
      if (sc > bs || (sc == bs && code < bi)) { bs = sc; bi = code; }         \
    }

  for (unsigned long long mm = m1; mm; mm &= mm - 1)
    RESCORE(__shfl(i1, __builtin_ctzll(mm)));
  for (unsigned long long mm = m2; mm; mm &= mm - 1)
    RESCORE(__shfl(i2, __builtin_ctzll(mm)));
  for (unsigned long long mm = mr; mm; mm &= mm - 1) {
    const int st = __builtin_ctzll(mm);
    for (int j = 0; j < 64; ++j) RESCORE(st * 64 + j);
  }
  #undef RESCORE

  if (lane == 0) out_idx[row] = (float)bi;

  // ---- phase 2: streamed outputs + loss partial ----
  {
    float* qrow = out_q + (size_t)row * KCODE;
    #pragma unroll
    for (int p = 0; p < 4; ++p) {
      const int col = p * 256 + lane * 4;
      f32x4 qv;
      qv.x = (col + 0 == bi) ? 1.0f : 0.0f;
      qv.y = (col + 1 == bi) ? 1.0f : 0.0f;
      qv.z = (col + 2 == bi) ? 1.0f : 0.0f;
      qv.w = (col + 3 == bi) ? 1.0f : 0.0f;
      __builtin_nontemporal_store(qv, (f32x4*)(qrow + col));
    }
  }

  const double ih = 1.0 / fmax(hnormd[row], 1e-6);
  const float* crow = cbn + (size_t)bi * DDIM;
  const f32x4 c0 = *(const f32x4*)(crow + lane * 4);
  const f32x4 c1 = *(const f32x4*)(crow + 256 + lane * 4);

  const size_t ro0 = (size_t)row * DDIM + lane * 4;
  const size_t ro1 = ro0 + 256;
  __builtin_nontemporal_store(c0, (f32x4*)(out_ct + ro0));
  __builtin_nontemporal_store(c1, (f32x4*)(out_ct + ro1));
  __builtin_nontemporal_store(c0, (f32x4*)(out_ch + ro0));
  __builtin_nontemporal_store(c1, (f32x4*)(out_ch + ro1));
  __builtin_nontemporal_store(c0, (f32x4*)(out_cq + ro0));
  __builtin_nontemporal_store(c1, (f32x4*)(out_cq + ro1));

  double ls = 0.0, e;
  e = (double)h0.x * ih - (double)c0.x; ls += e * e;
  e = (double)h0.y * ih - (double)c0.y; ls += e * e;
  e = (double)h0.z * ih - (double)c0.z; ls += e * e;
  e = (double)h0.w * ih - (double)c0.w; ls += e * e;
  e = (double)h1.x * ih - (double)c1.x; ls += e * e;
  e = (double)h1.y * ih - (double)c1.y; ls += e * e;
  e = (double)h1.z * ih - (double)c1.z; ls += e * e;
  e = (double)h1.w * ih - (double)c1.w; ls += e * e;
  #pragma unroll
  for (int m = 1; m < 64; m <<= 1) ls += __shfl_xor(ls, m);
  if (lane == 0) lsum[row] = ls;
}

__global__ __launch_bounds__(256) void k_loss(const double* __restrict__ lsum,
                                              float* __restrict__ out_loss) {
  const int tx = threadIdx.x;
  double s = 0.0;
  for (int i = tx; i < NROWS; i += 256) s += lsum[i];
  #pragma unroll
  for (int m = 1; m < 64; m <<= 1) s += __shfl_xor(s, m);
  __shared__ double sh[4];
  if ((tx & 63) == 0) sh[tx >> 6] = s;
  __syncthreads();
  if (tx == 0)
    out_loss[0] = (float)(1.25 * (sh[0] + sh[1] + sh[2] + sh[3]) / ((double)NROWS * (double)DDIM));
}

extern "C" void kernel_launch(void* const* d_in, const int* in_sizes, int n_in,
                              void* d_out, int out_size, void* d_ws, size_t ws_size,
                              hipStream_t stream) {
  const float* h = (const float*)d_in[0];
  const float* cb = (const float*)d_in[1];

  float* out = (float*)d_out;
  float* out_q    = out;
  float* out_ct   = out + 33554432;
  float* out_ch   = out + 50331648;
  float* out_cq   = out + 67108864;
  float* out_loss = out + 83886080;
  float* out_idx  = out + 83886081;

  char* ws = (char*)d_ws;
  unsigned short* AThi = (unsigned short*)(ws);               // 32 MB
  unsigned short* BThi = (unsigned short*)(ws + 33554432);    // 1 MB
  double* invcd  = (double*)(ws + 34603008);                  // 8 KB
  float*  invcf  = (float*)(ws + 34611200);                   // 4 KB
  float*  hnormf = (float*)(ws + 34615296);                   // 128 KB
  float*  cbnrmf = (float*)(ws + 34746368);                   // 4 KB (sink)
  float*  cbn    = (float*)(ws + 34750464);                   // 2 MB
  float4* pcand  = (float4*)(ws + 36847616);                  // 8 MB
  int*    pt3    = (int*)(ws + 45236224);                     // 2 MB
  double* lsum   = (double*)(ws + 47333376);                  // 256 KB
  double* hnormd = (double*)(ws + 47595520);                  // 256 KB
  double* cbnrmd = (double*)(ws + 47857664);                  // 8 KB (sink)

  k_invc<<<KCODE / 4, 256, 0, stream>>>(cb, invcd, invcf, cbn);
  k_prep<<<NROWS / 16, 256, 0, stream>>>(h, AThi, hnormf, hnormd);
  k_prep<<<KCODE / 16, 256, 0, stream>>>(cb, BThi, cbnrmf, cbnrmd);
  k_mfma<<<2048, 256, 0, stream>>>(AThi, BThi, invcf, hnormf, pcand, pt3);
  k_selwrite<<<NROWS / 4, 256, 0, stream>>>(h, cb, cbn, invcd, hnormd, hnormf,
                                            pcand, pt3,
                                            out_q, out_ct, out_ch, out_cq,
                                            out_idx, lsum);
  k_loss<<<1, 256, 0, stream>>>(lsum, out_loss);
}